// Round 8
// baseline (203.257 us; speedup 1.0000x reference)
//
#include <hip/hip_runtime.h>
#include <hip/hip_fp16.h>

// Problem constants (fixed by the reference)
constexpr int L = 64;     // sites
constexpr int P = 4;      // physical dim
constexpr int D = 128;    // bond dim
constexpr int B = 2048;   // batch
constexpr int EPW = 16;   // batch elements per WG (one mfma M-tile)
constexpr int NG = B / EPW;   // 128 batch groups -> 256 WGs (fwd+bwd)

using v8h = __attribute__((ext_vector_type(8))) _Float16;  // mfma A/B frag
using v4h = __attribute__((ext_vector_type(4))) _Float16;
using v4f = __attribute__((ext_vector_type(4))) float;     // mfma C/D frag

// ---- workspace layout (bytes); TOTAL 10 MB ------------------------------
constexpr size_t UT_OFF  = 0;               // u_t fp32 [d][b]   1 MB
constexpr size_t WT_OFF  = 1048576;         // w_t fp32 [d][b]   1 MB
constexpr size_t MTF_OFF = 2097152;         // sites 0..31  fp16 [mat][c][d] 4 MB
constexpr size_t MTB_OFF = 6291456;         // sites 32..63 fp16 [mat][d][c] 4 MB

// s_waitcnt immediates (gfx9: vmcnt[3:0] | exp<<4 | lgkm<<8 | vmcnt[5:4]<<14)
#define WAIT_LGKM0 0xC07F  // lgkmcnt(0) only; vmcnt untouched (prefetch lives)

// ---------------------------------------------------------------------------
// Convert fp32 [site][p][d][c]:
//   sites 32..63 -> mtb, row-major fp16 [d][c]  (bwd B-frags)
//   sites  0..31 -> mtf, transposed fp16 [c][d] (fwd B-frags)
// Both store element B^T[n][k] at mat_base + n*256B + k*2B (same formula).
// One matrix per WG; per-block-uniform path split. (R7-verified.)
// ---------------------------------------------------------------------------
__global__ void convert_dual(const float* __restrict__ src,
                             _Float16* __restrict__ mtf,
                             _Float16* __restrict__ mtb) {
  __shared__ _Float16 lt[128 * 136];  // pad 136 breaks banks
  const int mat = blockIdx.x;         // site*P + p
  const int site = mat >> 2;
  const float4* sb = (const float4*)(src + (size_t)mat * 16384);
  const int t = threadIdx.x;
  if (site >= 32) {                   // bwd half: straight cast, keep [d][c]
    _Float16* bb = mtb + (size_t)(mat - 128) * 16384;
#pragma unroll
    for (int it = 0; it < 16; ++it) {
      int idx = t + it * 256;         // 4096 float4 per matrix
      float4 f = sb[idx];
      v4h h4 = {(_Float16)f.x, (_Float16)f.y, (_Float16)f.z, (_Float16)f.w};
      *(v4h*)(bb + idx * 4) = h4;
    }
    return;
  }
  // fwd half: transpose via padded LDS (R3-verified pattern)
#pragma unroll
  for (int it = 0; it < 16; ++it) {
    int idx = t + it * 256;
    int row = idx >> 5, c4 = idx & 31;
    float4 f = sb[idx];
    lt[(c4 * 4 + 0) * 136 + row] = (_Float16)f.x;
    lt[(c4 * 4 + 1) * 136 + row] = (_Float16)f.y;
    lt[(c4 * 4 + 2) * 136 + row] = (_Float16)f.z;
    lt[(c4 * 4 + 3) * 136 + row] = (_Float16)f.w;
  }
  __syncthreads();
  _Float16* fb = mtf + (size_t)mat * 16384;
#pragma unroll
  for (int it = 0; it < 8; ++it) {
    int idx = t + it * 256;           // 2048 v8h per matrix
    int c = idx >> 4, d8 = idx & 15;
    *(v8h*)(fb + c * 128 + d8 * 8) = *(const v8h*)&lt[c * 136 + d8 * 8];
  }
}

// ---------------------------------------------------------------------------
// Half-chain kernel v2: 256 WGs x 8 waves x 16 elements; even blockIdx =
// fwd (sites 0..31 ascending, u = l^T prod M), odd = bwd (sites 63..32
// descending, w = prod M r; same GEMM via row-major mtb).
//
// R8 change (LDS-pipe was the binding resource at R7's 59.6 us): B-frags
// load global->VGPR DIRECTLY (16 B/lane, 64-B runs per column), register
// double-buffered one full site ahead — no global_load_lds, no matrix LDS.
// Each byte was LDS-read exactly once in R7, so the LDS hop was pure cost.
// Site barrier is raw s_waitcnt lgkmcnt(0) + s_barrier: it protects only
// the v-exchange (pure LDS); B-data is wave-private registers, so vmcnt
// prefetch legitimately survives the barrier. Compiler auto-inserts
// vmcnt(N) before consuming cur-site registers (16 nxt loads in flight).
// Frag layouts (R2/R7-verified): A[m=lane&15][k=q4*8+j],
// B^T[n=lane&15][k=q4*8+j], C[row=q4*4+r][col=lane&15].
// v in LDS fp16 [e][d], 16B-unit XOR swizzle (slot ^= e&7), double-buffered.
// ---------------------------------------------------------------------------
__global__ __launch_bounds__(512, 1) void mps_half_chain2(
    const int* __restrict__ onstate, const _Float16* __restrict__ mtf,
    const _Float16* __restrict__ mtb, const float* __restrict__ left_vec,
    const float* __restrict__ right_vec, float* __restrict__ ut,
    float* __restrict__ wt) {
  __shared__ _Float16 vlds[2][EPW * D];   // 2 x 4 KB, swizzled
  __shared__ int plds[L * EPW];           // 4 KB
  const int tid = threadIdx.x;
  const int wave = tid >> 6, lane = tid & 63;
  const int me = lane & 15, q4 = lane >> 4;
  const bool fwd = !(blockIdx.x & 1);
  const int b0 = (blockIdx.x >> 1) * EPW;
  const _Float16* mbase = fwd ? mtf : mtb;   // my half's 128 matrices
  const float* ivec = fwd ? left_vec : right_vec;
  float* ovec = fwd ? ut : wt;

  // ---- stage onstate -> plds[site][e] (global site index)
#pragma unroll
  for (int j = 0; j < 2; ++j) {
    int idx = tid + j * 512;
    int e = idx >> 6, i = idx & 63;
    plds[i * EPW + e] = onstate[(b0 + e) * L + i];
  }
  // ---- init v = ivec for every element (swizzled fp16)
  if (tid < 256) {
    int e = tid >> 4, seg = tid & 15;
    _Float16* vp = &vlds[0][e * 128 + (seg ^ (e & 7)) * 8];
#pragma unroll
    for (int j = 0; j < 8; ++j) vp[j] = (_Float16)ivec[seg * 8 + j];
  }

  // per-lane global base: my column (wave*16+me), my k-segment (q4*16 B)
  const char* lb = (const char*)mbase + (wave * 16 + me) * 256 + q4 * 16;
  const int c0 = wave * 16 + me;      // my output column

  // load one site's 16 B-frags (2 halves x 4 p x 2 kc) into registers
  auto loadsite = [&](int ls, v8h (&dst)[2][8]) {
    const char* sbase = lb + (size_t)ls * 131072;
#pragma unroll
    for (int h = 0; h < 2; ++h)
#pragma unroll
      for (int p = 0; p < P; ++p)
#pragma unroll
        for (int kc = 0; kc < 2; ++kc)
          dst[h][p * 2 + kc] =
              *(const v8h*)(sbase + p * 32768 + h * 128 + kc * 64);
  };
  // consume k-half h from register frags (masked by pm), A-frags from vb
  auto consume = [&](const v8h (&bb)[8], int h, int pm, const char* vb,
                     v4f& acc) {
    const int s0 = h * 8 + q4, s1 = h * 8 + 4 + q4;
    v8h a0 = *(const v8h*)(vb + me * 256 + (s0 ^ (me & 7)) * 16);
    v8h a1 = *(const v8h*)(vb + me * 256 + (s1 ^ (me & 7)) * 16);
#pragma unroll
    for (int p = 0; p < P; ++p) {
      const bool isp = (pm == p);
      v8h zf = {};
      v8h am0 = isp ? a0 : zf;
      v8h am1 = isp ? a1 : zf;
      acc = __builtin_amdgcn_mfma_f32_16x16x32_f16(am0, bb[p * 2 + 0], acc,
                                                   0, 0, 0);
      acc = __builtin_amdgcn_mfma_f32_16x16x32_f16(am1, bb[p * 2 + 1], acc,
                                                   0, 0, 0);
    }
  };

  v8h bufA[2][8], bufB[2][8];         // ping-pong site buffers (128 VGPR)
  loadsite(fwd ? 0 : 31, bufA);       // prologue: site 0 -> A
  __syncthreads();                    // plds/vlds init visibility

  v4f accL = {0.f, 0.f, 0.f, 0.f};
  // one site step: prefetch next into nxt, consume cur, exchange v
  auto step = [&](int site, v8h (&cur)[2][8], v8h (&nxt)[2][8]) {
    const int site_g = fwd ? site : 63 - site;   // global site (plds index)
    const int pm = plds[site_g * EPW + me];
    const char* vb = (const char*)vlds[site & 1];
    if (site < 31) loadsite(fwd ? site + 1 : 30 - site, nxt);
    v4f acc = {0.f, 0.f, 0.f, 0.f};
    consume(cur[0], 0, pm, vb, acc);
    consume(cur[1], 1, pm, vb, acc);
    if (site < 31) {
      // v-exchange: write v_new fp16 (C-layout rows) to the other buffer
      _Float16* vn = (_Float16*)vlds[(site & 1) ^ 1];
#pragma unroll
      for (int r = 0; r < 4; ++r) {
        int e = q4 * 4 + r;
        vn[e * 128 + ((c0 >> 3) ^ (e & 7)) * 8 + (c0 & 7)] = (_Float16)acc[r];
      }
      // LDS-only barrier: ds_writes drained; register prefetch stays live
      __builtin_amdgcn_s_waitcnt(WAIT_LGKM0);
      __builtin_amdgcn_s_barrier();
    } else {
      accL = acc;
    }
  };

#pragma unroll 1
  for (int s2 = 0; s2 < 16; ++s2) {   // ping-pong: no register copies
    step(2 * s2 + 0, bufA, bufB);
    step(2 * s2 + 1, bufB, bufA);
  }

  // ---- epilogue: store half-chain vector transposed [d][b] (fp32)
#pragma unroll
  for (int r = 0; r < 4; ++r) ovec[c0 * B + b0 + q4 * 4 + r] = accL[r];
}

// ---------------------------------------------------------------------------
// Combine: amp[b] = sum_d u[d][b] * w[d][b]  (coalesced along b)
// ---------------------------------------------------------------------------
__global__ void combine_uw(const float* __restrict__ ut,
                           const float* __restrict__ wt,
                           float* __restrict__ out) {
  const int b = blockIdx.x * 256 + threadIdx.x;
  float s = 0.f;
#pragma unroll 8
  for (int d = 0; d < D; ++d) s += ut[d * B + b] * wt[d * B + b];
  out[b] = s;
}

// ---------------------------------------------------------------------------
extern "C" void kernel_launch(void* const* d_in, const int* in_sizes, int n_in,
                              void* d_out, int out_size, void* d_ws,
                              size_t ws_size, hipStream_t stream) {
  const int*   onstate      = (const int*)d_in[0];
  const float* site_tensors = (const float*)d_in[1];
  const float* left_vec     = (const float*)d_in[2];
  const float* right_vec    = (const float*)d_in[3];
  float*       out          = (float*)d_out;
  char*        ws           = (char*)d_ws;   // needs 10 MB
  float*       ut           = (float*)(ws + UT_OFF);
  float*       wt           = (float*)(ws + WT_OFF);
  _Float16*    mtf          = (_Float16*)(ws + MTF_OFF);
  _Float16*    mtb          = (_Float16*)(ws + MTB_OFF);

  convert_dual<<<L * P, 256, 0, stream>>>(site_tensors, mtf, mtb);
  mps_half_chain2<<<2 * NG, 512, 0, stream>>>(
      onstate, mtf, mtb, left_vec, right_vec, ut, wt);
  combine_uw<<<B / 256, 256, 0, stream>>>(ut, wt, out);
}

// Round 9
// 132.341 us; speedup vs baseline: 1.5359x; 1.5359x over previous
//
#include <hip/hip_runtime.h>
#include <hip/hip_fp16.h>

// Problem constants (fixed by the reference)
constexpr int L = 64;     // sites
constexpr int P = 4;      // physical dim
constexpr int D = 128;    // bond dim
constexpr int B = 2048;   // batch
constexpr int EPW = 16;   // batch elements per WG (one mfma M-tile)
constexpr int NG = B / EPW;   // 128 batch groups -> 256 WGs (fwd+bwd)

using v8h = __attribute__((ext_vector_type(8))) _Float16;  // mfma A/B frag
using v4h = __attribute__((ext_vector_type(4))) _Float16;
using v4f = __attribute__((ext_vector_type(4))) float;     // mfma C/D frag

// ---- workspace layout (bytes); TOTAL 10 MB ------------------------------
constexpr size_t UT_OFF  = 0;               // u_t fp32 [d][b]   1 MB
constexpr size_t WT_OFF  = 1048576;         // w_t fp32 [d][b]   1 MB
constexpr size_t MTF_OFF = 2097152;         // sites 0..31  fp16 [mat][c][d] 4 MB
constexpr size_t MTB_OFF = 6291456;         // sites 32..63 fp16 [mat][d][c] 4 MB

// ---- chain-kernel LDS map (bytes) ---------------------------------------
constexpr int VLDS0 = 131072;
constexpr int VLDS1 = 131072 + 4096;
constexpr int PLDS  = 131072 + 8192;
constexpr int SMEM_BYTES = PLDS + L * EPW * 4;  // 143360 -> 1 WG/CU, 8 waves

// s_waitcnt immediates (gfx9: vmcnt[3:0] | exp<<4 | lgkm<<8 | vmcnt[5:4]<<14)
#define WAIT_VM8   0xF78   // vmcnt(8) — drain all but the newest 8 loads
#define WAIT_VM0   0xF70   // vmcnt(0)
#define WAIT_LGKM0 0xC07F  // lgkmcnt(0) only; vmcnt untouched

__device__ __forceinline__ void gl2lds16(const void* g, void* l) {
  __builtin_amdgcn_global_load_lds(
      (const __attribute__((address_space(1))) void*)g,
      (__attribute__((address_space(3))) void*)l, 16, 0, 0);
}

// ---------------------------------------------------------------------------
// Convert fp32 [site][p][d][c]:
//   sites 32..63 -> mtb, row-major fp16 [d][c]  (bwd B-frags) — straight cast
//   sites  0..31 -> mtf, transposed fp16 [c][d] (fwd B-frags) — REGISTER
//     transpose, no LDS (R7's LDS path had 16-way bank conflicts: store
//     stride 1088 B -> dword-bank stride 272 % 32 == 16).
//   Thread (c=lane, d8): 8 loads of A[d8*8+j][c], each coalesced along c
//   (lanes stride 4 B -> 256 B/wave); one v8h store to mtf[c][d8*8]
//   (scattered 16 B, ~4x write inflation on 4 MB — a few us, acceptable).
// ---------------------------------------------------------------------------
__global__ void convert_dual(const float* __restrict__ src,
                             _Float16* __restrict__ mtf,
                             _Float16* __restrict__ mtb) {
  const int mat = blockIdx.x;         // site*P + p
  const int site = mat >> 2;
  const int t = threadIdx.x;
  if (site >= 32) {                   // bwd half: straight cast, keep [d][c]
    const float4* sb = (const float4*)(src + (size_t)mat * 16384);
    _Float16* bb = mtb + (size_t)(mat - 128) * 16384;
#pragma unroll
    for (int it = 0; it < 16; ++it) {
      int idx = t + it * 256;         // 4096 float4 per matrix
      float4 f = sb[idx];
      v4h h4 = {(_Float16)f.x, (_Float16)f.y, (_Float16)f.z, (_Float16)f.w};
      *(v4h*)(bb + idx * 4) = h4;
    }
    return;
  }
  // fwd half: register transpose
  const float* sb = src + (size_t)mat * 16384;
  _Float16* fb = mtf + (size_t)mat * 16384;
  const int cl = t & 63;              // c within 64-lane run (coalesced dim)
  const int dg = t >> 6;              // d8 group 0..3
#pragma unroll
  for (int ch = 0; ch < 2; ++ch) {    // c halves
    const int c = ch * 64 + cl;
#pragma unroll
    for (int dh = 0; dh < 4; ++dh) {  // d8 = dh*4 + dg
      const int d8 = dh * 4 + dg;
      v8h v;
#pragma unroll
      for (int j = 0; j < 8; ++j) v[j] = (_Float16)sb[(d8 * 8 + j) * D + c];
      *(v8h*)(fb + c * D + d8 * 8) = v;
    }
  }
}

// ---------------------------------------------------------------------------
// Half-chain kernel (R7-verified, verbatim): 256 WGs x 8 waves x 16
// elements; even blockIdx = fwd (sites 0..31 ascending, u = l^T prod M),
// odd = bwd (sites 63..32 descending, w = prod M r; same GEMM via mtb).
// Sync discipline:
//  - site boundary: __syncthreads (drains vmcnt+lgkm).
//  - before DMA-writing buf0 (h=1 prefetch): s_waitcnt lgkmcnt(0) fence —
//    ds_read (lgkm) and global_load_lds DMA (vmcnt) are UNORDERED in HW
//    (the R4-R6 corruption); sched_barriers pin compiler order.
//  - h=1 consume: vmcnt(8) drains exactly the chunk about to be read.
// Frag layouts: A[m=lane&15][k=q4*8+j], B^T[n=lane&15][k=q4*8+j],
// C[row=q4*4+r][col=lane&15]. Chunk LDS: [p][c16][kseg8] 16B units,
// kseg slot ^= (c&7); staging bakes inverse swizzle into global address.
// ---------------------------------------------------------------------------
__global__ __launch_bounds__(512, 1) void mps_half_chain(
    const int* __restrict__ onstate, const _Float16* __restrict__ mtf,
    const _Float16* __restrict__ mtb, const float* __restrict__ left_vec,
    const float* __restrict__ right_vec, float* __restrict__ ut,
    float* __restrict__ wt) {
  extern __shared__ char smem[];
  const int tid = threadIdx.x;
  const int wave = tid >> 6, lane = tid & 63;
  const int me = lane & 15, q4 = lane >> 4;
  const bool fwd = !(blockIdx.x & 1);
  const int b0 = (blockIdx.x >> 1) * EPW;
  const _Float16* mbase = fwd ? mtf : mtb;   // my half's 128 matrices
  const float* ivec = fwd ? left_vec : right_vec;
  float* ovec = fwd ? ut : wt;

  // ---- stage onstate -> plds[site][e] (global site index)
  int* plds = (int*)(smem + PLDS);
#pragma unroll
  for (int j = 0; j < 2; ++j) {
    int idx = tid + j * 512;
    int e = idx >> 6, i = idx & 63;
    plds[i * EPW + e] = onstate[(b0 + e) * L + i];
  }
  // ---- init v = ivec for every element (swizzled fp16)
  if (tid < 256) {
    int e = tid >> 4, seg = tid & 15;
    _Float16* vp = (_Float16*)(smem + VLDS0) + e * 128 + (seg ^ (e & 7)) * 8;
#pragma unroll
    for (int j = 0; j < 8; ++j) vp[j] = (_Float16)ivec[seg * 8 + j];
  }

  char* wbuf = smem + wave * 16384;   // my private 2 x 8 KB chunk buffers

  // per-lane, site-invariant staging source offsets (inverse swizzle baked)
  int soff[8];
#pragma unroll
  for (int i = 0; i < 8; ++i) {
    int u = i * 64 + lane;
    int p = u >> 7, r = u & 127, cl = r >> 3, slot = r & 7;
    soff[i] = p * 32768 + (wave * 16 + cl) * 256 + (slot ^ (cl & 7)) * 16;
  }
  // stage chunk (local site ls in 0..31, k-half h) into buffer z
  auto stage = [&](int ls, int h, int z) {
    const char* gb = (const char*)mbase + (size_t)ls * 131072 + h * 128;
    char* lb = wbuf + z * 8192;
#pragma unroll
    for (int i = 0; i < 8; ++i) gl2lds16(gb + soff[i], lb + i * 1024);
  };
  // consume k-half h of the chunk in buffer z into acc (masked by pm)
  auto consume = [&](int h, int z, int pm, const char* vb, v4f& acc) {
    const int s0 = h * 8 + q4, s1 = h * 8 + 4 + q4;
    v8h a0 = *(const v8h*)(vb + me * 256 + (s0 ^ (me & 7)) * 16);
    v8h a1 = *(const v8h*)(vb + me * 256 + (s1 ^ (me & 7)) * 16);
    const char* cb = wbuf + z * 8192;
#pragma unroll
    for (int p = 0; p < P; ++p) {
      const bool isp = (pm == p);
      v8h zf = {};
      v8h am0 = isp ? a0 : zf;
      v8h am1 = isp ? a1 : zf;
      const char* pb = cb + p * 2048 + me * 128;
      v8h bf0 = *(const v8h*)(pb + ((q4) ^ (me & 7)) * 16);
      v8h bf1 = *(const v8h*)(pb + ((4 + q4) ^ (me & 7)) * 16);
      acc = __builtin_amdgcn_mfma_f32_16x16x32_f16(am0, bf0, acc, 0, 0, 0);
      acc = __builtin_amdgcn_mfma_f32_16x16x32_f16(am1, bf1, acc, 0, 0, 0);
    }
  };

  stage(fwd ? 0 : 31, 0, 0);          // prologue: chunk g=0 -> buf0
  __syncthreads();                    // drains everything (incl. prologue)

  const int c0 = wave * 16 + me;      // my output column
  v4f accL = {0.f, 0.f, 0.f, 0.f};
  for (int site = 0; site < 32; ++site) {
    const int site_g = fwd ? site : 63 - site;   // global site (plds index)
    const int ls     = fwd ? site : 31 - site;   // local site in my half
    const int pm = plds[site_g * EPW + me];
    const char* vb = smem + ((site & 1) ? VLDS1 : VLDS0);
    v4f acc = {0.f, 0.f, 0.f, 0.f};

    // ---- h = 0: issue (ls, h=1) -> buf1; consume buf0 (barrier-drained)
    stage(ls, 1, 1);
    consume(0, 0, pm, vb, acc);

    // ---- h = 1
    if (site < 31) {
      const int lsn = fwd ? site + 1 : 30 - site;
      // hazard fence: drain my LDS-pipe reads of buf0 before DMA-writing it
      __builtin_amdgcn_sched_barrier(0);
      __builtin_amdgcn_s_waitcnt(WAIT_LGKM0);
      __builtin_amdgcn_sched_barrier(0);
      stage(lsn, 0, 0);                         // prefetch next site -> buf0
      __builtin_amdgcn_s_waitcnt(WAIT_VM8);     // drain buf1 only
      consume(1, 1, pm, vb, acc);
      // v-exchange: write v_new fp16 (C-layout rows) to the other buffer
      _Float16* vn = (_Float16*)(smem + ((site & 1) ? VLDS0 : VLDS1));
#pragma unroll
      for (int r = 0; r < 4; ++r) {
        int e = q4 * 4 + r;
        vn[e * 128 + ((c0 >> 3) ^ (e & 7)) * 8 + (c0 & 7)] = (_Float16)acc[r];
      }
      __syncthreads();
    } else {
      __builtin_amdgcn_s_waitcnt(WAIT_VM0);     // last chunk: full drain
      consume(1, 1, pm, vb, acc);
      accL = acc;
    }
  }
  // ---- epilogue: store half-chain vector transposed [d][b] (fp32)
#pragma unroll
  for (int r = 0; r < 4; ++r) ovec[c0 * B + b0 + q4 * 4 + r] = accL[r];
}

// ---------------------------------------------------------------------------
// Combine: amp[b] = sum_d u[d][b] * w[d][b]  (coalesced along b)
// ---------------------------------------------------------------------------
__global__ void combine_uw(const float* __restrict__ ut,
                           const float* __restrict__ wt,
                           float* __restrict__ out) {
  const int b = blockIdx.x * 256 + threadIdx.x;
  float s = 0.f;
#pragma unroll 8
  for (int d = 0; d < D; ++d) s += ut[d * B + b] * wt[d * B + b];
  out[b] = s;
}

// ---------------------------------------------------------------------------
extern "C" void kernel_launch(void* const* d_in, const int* in_sizes, int n_in,
                              void* d_out, int out_size, void* d_ws,
                              size_t ws_size, hipStream_t stream) {
  const int*   onstate      = (const int*)d_in[0];
  const float* site_tensors = (const float*)d_in[1];
  const float* left_vec     = (const float*)d_in[2];
  const float* right_vec    = (const float*)d_in[3];
  float*       out          = (float*)d_out;
  char*        ws           = (char*)d_ws;   // needs 10 MB
  float*       ut           = (float*)(ws + UT_OFF);
  float*       wt           = (float*)(ws + WT_OFF);
  _Float16*    mtf          = (_Float16*)(ws + MTF_OFF);
  _Float16*    mtb          = (_Float16*)(ws + MTB_OFF);

  hipFuncSetAttribute((const void*)mps_half_chain,
                      hipFuncAttributeMaxDynamicSharedMemorySize, SMEM_BYTES);

  convert_dual<<<L * P, 256, 0, stream>>>(site_tensors, mtf, mtb);
  mps_half_chain<<<2 * NG, 512, SMEM_BYTES, stream>>>(
      onstate, mtf, mtb, left_vec, right_vec, ut, wt);
  combine_uw<<<B / 256, 256, 0, stream>>>(ut, wt, out);
}